// Round 18
// baseline (90.785 us; speedup 1.0000x reference)
//
#include <hip/hip_runtime.h>

// ---------------------------------------------------------------------------
// FFT_Conv_Layer == 3x3 "same" spatial conv with flipped REAL filter plane:
//   out[b,o,y,x] = sum_{i,ky,kx} filts[0,i,o,ky,kx,0] * img[b,i,y+1-ky,x+1-kx]
//
// Ladder: R2 22.54 | R7 21.24 (+swz) | R8 21.07 | R9/R10 ~21 | R13 23.98.
// R14 diagnostic (REPS=6, 39.73us): marginal [K+store] = 3.73us -> compute+
// store is NOT the problem; ~13-15us is stage+launch+fixed. R16 attacks that:
//   (1) ONE dispatch: weights gathered per-wave into 144 VGPRs (filts is
//       L2-resident; 288 scalar loads overlap staging) -> no prep_w, no ws,
//       and the K-loop loses its global B-loads (pure ds_read+MFMA).
//   (2) 4-row blocks (256 x 512thr, 6 slabs): staged reads 33.6 -> 25.2 MB.
//   Geometry/swizzles/C-layout = R7-verified verbatim.
// (R16/R17 benches lost to an unresponsive container; resubmitted unchanged.)
// ---------------------------------------------------------------------------

typedef _Float16 f16x8 __attribute__((ext_vector_type(8)));
typedef float    f32x4 __attribute__((ext_vector_type(4)));

#define NB 16
#define NC 64
#define NH 64
#define NW 64
#define CHUNKS 528                 // 66 xp positions * 8 channel-chunks per slab
#define SLAB_BYTES (CHUNKS * 16)   // 8448 B per image row slab

// ---------------------------------------------------------------------------
// conv_fused: 256 blocks (XCD-swizzled) = (b, 4-row quad), 8 waves (512 thr).
//   LDS: 6 slabs = image rows y0-1 .. y0+4 (50,688 B).
//   Staging: 48 jobs (slab sl = j/8, chunk ci = j%8); wave w takes j = w+8k.
//     Per job: 8 coalesced f32 loads at x=lane, cvt f16, one swizzled
//     ds_write_b128: chunk = xp*8 + (ci^(xp&7)). Pads: tid<96 zero xp=0,65.
//   Weights: wave w (oh = w&1) gathers its 36 B-fragments into wreg[9][2][2]
//     (static indices -> VGPRs): wreg[t][kc][n][e] =
//     filts[(((kc*32+h*8+e)*64 + oh*32+n*16+r)*9 + t)*2]  (f32 -> f16).
//   Compute: wave w = (row w>>1, oh w&1): 4x2 16x16 frags; K = 3ky*3kx*2kc:
//     4 A ds_reads + 8 MFMA per step, B from registers.
//   C/D layout (m89/m91-verified): o = n*16+(lane&15), x = m*16+(lane>>4)*4+j
// ---------------------------------------------------------------------------
__global__ __launch_bounds__(512, 2) void conv_fused(const float* __restrict__ imgs,
                                                     const float* __restrict__ filts,
                                                     float* __restrict__ out) {
    __shared__ char lds[6 * SLAB_BYTES];   // 50,688 B
    const int bid = blockIdx.x;
    const int swz = ((bid & 7) << 5) | (bid >> 3);   // bijective: 256 = 8*32
    const int b   = swz >> 4;
    const int y0  = (swz & 15) << 2;     // first of 4 output rows
    const int tid = threadIdx.x;
    const int w   = tid >> 6;            // wave 0..7
    const int l   = tid & 63;
    const int h   = l >> 4;              // k-chunk lane group
    const int r   = l & 15;              // A-row / B-col within fragment
    const int oh  = w & 1;               // outC half owned by this wave

    // ---- zero pads: 6 slabs x 16 chunks (xp = 0, 65) ----
    if (tid < 96) {
        const int sl  = tid >> 4;
        const int rem = tid & 15;
        const int ci  = rem >> 1;
        const int xp2 = (rem & 1) ? 65 : 0;
        const int c2  = xp2 * 8 + (ci ^ (xp2 & 7));
        f16x8 z;
        #pragma unroll
        for (int k = 0; k < 8; ++k) z[k] = (_Float16)0.f;
        *reinterpret_cast<f16x8*>(lds + sl * SLAB_BYTES + c2 * 16) = z;
    }

    // ---- stage 6 slabs (image rows y0-1 .. y0+4), 48 jobs over 8 waves ----
    #pragma unroll
    for (int j = 0; j < 6; ++j) {
        const int job = w + j * 8;
        const int sl  = job >> 3;        // slab 0..5
        const int ci  = job & 7;         // channel chunk
        const int yy  = y0 - 1 + sl;
        float fr[8];
        if ((unsigned)yy < (unsigned)NH) {
            const float* src = imgs + (((size_t)(b * NC + ci * 8)) * NH + yy) * NW + l;
            #pragma unroll
            for (int k = 0; k < 8; ++k) fr[k] = src[(size_t)k * NH * NW];
        } else {
            #pragma unroll
            for (int k = 0; k < 8; ++k) fr[k] = 0.f;
        }
        f16x8 v;
        #pragma unroll
        for (int k = 0; k < 8; ++k) v[k] = (_Float16)fr[k];
        const int xp = l + 1;            // lane covers x = l
        const int chunk = xp * 8 + (ci ^ (xp & 7));
        *reinterpret_cast<f16x8*>(lds + sl * SLAB_BYTES + chunk * 16) = v;
    }

    // ---- gather this wave's 36 weight fragments into registers ----
    // addr(floats) = i*1152 + o*18 + 2t ; i = kc*32+h*8+e, o = oh*32+n*16+r
    f16x8 wreg[9][2][2];
    {
        const float* fb = filts + (size_t)(h * 9216 + oh * 576 + r * 18);
        #pragma unroll
        for (int t = 0; t < 9; ++t)
            #pragma unroll
            for (int kc = 0; kc < 2; ++kc)
                #pragma unroll
                for (int n = 0; n < 2; ++n) {
                    f16x8 v;
                    #pragma unroll
                    for (int e = 0; e < 8; ++e)
                        v[e] = (_Float16)fb[kc * 36864 + e * 1152 + n * 288 + t * 2];
                    wreg[t][kc][n] = v;
                }
    }
    __syncthreads();

    const int row = w >> 1;              // output row within quad (0..3)

    f32x4 acc[4][2];
    #pragma unroll
    for (int m = 0; m < 4; ++m)
        #pragma unroll
        for (int n = 0; n < 2; ++n)
            acc[m][n] = f32x4{0.f, 0.f, 0.f, 0.f};

    #pragma unroll
    for (int ky = 0; ky < 3; ++ky) {
        const char* slab = lds + (row + 2 - ky) * SLAB_BYTES;   // sl in 0..5
        #pragma unroll
        for (int kx = 0; kx < 3; ++kx) {
            const int t = ky * 3 + kx;
            #pragma unroll
            for (int kc = 0; kc < 2; ++kc) {
                f16x8 a[4];
                #pragma unroll
                for (int m = 0; m < 4; ++m) {
                    const int xp = m * 16 + r + 2 - kx;          // 0..65
                    const int chunk = xp * 8 + (((kc << 2) + h) ^ (xp & 7));
                    a[m] = *reinterpret_cast<const f16x8*>(slab + chunk * 16);
                }
                #pragma unroll
                for (int m = 0; m < 4; ++m)
                    #pragma unroll
                    for (int n = 0; n < 2; ++n)
                        acc[m][n] = __builtin_amdgcn_mfma_f32_16x16x32_f16(a[m], wreg[t][kc][n], acc[m][n], 0, 0, 0);
            }
        }
    }

    const int y = y0 + row;
    #pragma unroll
    for (int m = 0; m < 4; ++m) {
        const int x0 = m * 16 + h * 4;
        #pragma unroll
        for (int n = 0; n < 2; ++n) {
            const int o = oh * 32 + n * 16 + r;
            *reinterpret_cast<f32x4*>(out + (((size_t)(b * 64 + o) * 64 + y) * 64) + x0) = acc[m][n];
        }
    }
}

extern "C" void kernel_launch(void* const* d_in, const int* in_sizes, int n_in,
                              void* d_out, int out_size, void* d_ws, size_t ws_size,
                              hipStream_t stream) {
    const float* imgs  = (const float*)d_in[0];   // [16][64][64][64] f32
    const float* filts = (const float*)d_in[1];   // [1][64][64][3][3][2] f32
    float* out = (float*)d_out;                   // [16][64][64][64] f32
    (void)d_ws; (void)ws_size;                    // no workspace needed

    hipLaunchKernelGGL(conv_fused, dim3(256), dim3(512), 0, stream, imgs, filts, out);
}